// Round 6
// baseline (249.557 us; speedup 1.0000x reference)
//
#include <hip/hip_runtime.h>
#include <hip/hip_bf16.h>

// ALiBi attention, B=8 L=1024 H=8 E=64, fp32 in/out, bf16 MFMA inside.
// Outputs: V [B,L,H,E] then series [B,H,L,L] concatenated in d_out.
// R6: prep kernel -> bf16 K [bh][s][e] and V^T [bh][e][s] in d_ws.
// Main kernel: two-pass fixed-max softmax, swapped QK^T (mfma(K,Q)).
// PV uses mfma_f32_16x16x16_bf16 whose A-frag layout EXACTLY matches the
// QK D-frag (k = 4*kg + j), so P never leaves registers: no LDS, no
// barriers, no cross-lane ops. P written to global straight from D-frag.

typedef short short8 __attribute__((ext_vector_type(8)));
typedef short short4v __attribute__((ext_vector_type(4)));
typedef float f32x4 __attribute__((ext_vector_type(4)));
typedef unsigned short u16x4 __attribute__((ext_vector_type(4)));

#define B_ 8
#define L_ 1024
#define H_ 8
#define E_ 64
#define RSTRIDE (H_ * E_)  // 512 floats between seq rows of Q/K/V
#define QBLK 64            // 4 waves x 16 q-rows

__device__ __forceinline__ unsigned short f2bf(float f) {
  return __builtin_bit_cast(unsigned short, __float2bfloat16(f));
}
// load 8 consecutive fp32 -> bf16x8 fragment (Q only)
__device__ __forceinline__ short8 ldfrag(const float* p) {
  float4 a = *reinterpret_cast<const float4*>(p);
  float4 b = *reinterpret_cast<const float4*>(p + 4);
  return (short8){(short)f2bf(a.x), (short)f2bf(a.y), (short)f2bf(a.z),
                  (short)f2bf(a.w), (short)f2bf(b.x), (short)f2bf(b.y),
                  (short)f2bf(b.z), (short)f2bf(b.w)};
}

__device__ __forceinline__ f32x4 mfma16(short4v a, short4v b, f32x4 c) {
#if __has_builtin(__builtin_amdgcn_mfma_f32_16x16x16bf16_1k)
  return __builtin_amdgcn_mfma_f32_16x16x16bf16_1k(a, b, c, 0, 0, 0);
#else
  asm volatile(
      "s_nop 1\n\t"
      "v_mfma_f32_16x16x16_bf16 %0, %1, %2, %0\n\t"
      "s_nop 2"
      : "+v"(c)
      : "v"(a), "v"(b));
  return c;
#endif
}

// ---- prep: Kbf[bh][s][e] bf16; VT[bh][e][s] bf16. grid 16*64, 256 thr ----
__global__ __launch_bounds__(256, 4) void prep_kv(
    const float* __restrict__ Kg, const float* __restrict__ Vg,
    unsigned short* __restrict__ Kbf, unsigned short* __restrict__ VTbf) {
  __shared__ unsigned short tile[64 * 64];  // V^T subtile [e][s], swizzled

  const int t = threadIdx.x;
  const int id = blockIdx.x;
  const int bh = id & 63;  // id%8 = h -> same XCD as main kernel's consumers
  const int sc = id >> 6;  // s-chunk 0..15
  const int h = bh & 7, b = bh >> 3;
  const int s0 = sc * 64;

  const float* Kb = Kg + ((size_t)b * L_ + s0) * RSTRIDE + h * E_;
  const float* Vb = Vg + ((size_t)b * L_ + s0) * RSTRIDE + h * E_;
  unsigned short* Ko = Kbf + ((size_t)bh * L_ + s0) * E_;
  unsigned short* Vo = VTbf + (size_t)bh * E_ * L_ + s0;  // row stride L_

  {  // K convert (coalesced both sides)
    const int e = 4 * (t & 15);
#pragma unroll
    for (int i = 0; i < 4; ++i) {
      const int s = (t >> 4) + 16 * i;
      float4 v = *reinterpret_cast<const float4*>(&Kb[(size_t)s * RSTRIDE + e]);
      *reinterpret_cast<u16x4*>(&Ko[s * 64 + e]) =
          (u16x4){f2bf(v.x), f2bf(v.y), f2bf(v.z), f2bf(v.w)};
    }
  }
  {  // V transpose into LDS (lane owns column e; coalesced reads)
    const int e = t & 63, w = t >> 6;
#pragma unroll
    for (int i = 0; i < 4; ++i) {
      const int s4 = 4 * w + 16 * i;
      const float* vp = &Vb[(size_t)s4 * RSTRIDE + e];
      u16x4 u = {f2bf(vp[0]), f2bf(vp[RSTRIDE]), f2bf(vp[2 * RSTRIDE]),
                 f2bf(vp[3 * RSTRIDE])};
      *reinterpret_cast<u16x4*>(
          &tile[e * 64 + (((s4 >> 3) ^ (e & 7)) << 3) + (s4 & 7)]) = u;
    }
  }
  __syncthreads();
  {  // write V^T rows (32B contiguous per thread)
    const int e = t >> 2;
    const int sb = 16 * (t & 3);
#pragma unroll
    for (int i = 0; i < 4; ++i) {
      const int sp = sb + 4 * i;
      u16x4 u = *reinterpret_cast<const u16x4*>(
          &tile[e * 64 + (((sp >> 3) ^ (e & 7)) << 3) + (sp & 7)]);
      *reinterpret_cast<u16x4*>(&Vo[(size_t)e * L_ + sp]) = u;
    }
  }
}

// ---- main: no LDS, no barriers, P register-resident ----
__global__ __launch_bounds__(256, 4) void alibi_attn(
    const float* __restrict__ Qg, const unsigned short* __restrict__ Kbf,
    const unsigned short* __restrict__ VTbf, float* __restrict__ Vout,
    float* __restrict__ Pout) {
  const int t = threadIdx.x;
  const int lane = t & 63;
  const int w = t >> 6;
  const int col = lane & 15;
  const int kg = lane >> 4;

  const int id = blockIdx.x;  // id%8 = h -> XCD-pinned K/VT in L2
  const int qb = id >> 6;
  const int bh = id & 63;
  const int h = bh & 7;
  const int b = bh >> 3;
  const int q0 = qb * QBLK;

  const float sc_l2e = 0.125f * 1.44269504f;
  const float sl_l2e = exp2f(-(float)(h + 1) * 0.125f) * 1.44269504f;

  const unsigned short* Kb = Kbf + (size_t)bh * (L_ * E_);
  const unsigned short* VTb = VTbf + (size_t)bh * (E_ * L_);

  // Q B-fragments: q-row = col, k = 8*kg + j (+32 for second slice)
  short8 qf0, qf1;
  {
    const float* qp =
        Qg + ((size_t)b * L_ + q0 + 16 * w + col) * RSTRIDE + h * E_ + 8 * kg;
    qf0 = ldfrag(qp);
    qf1 = ldfrag(qp + 32);
  }

  // per-lane key base for this lane's D-frag rows: key = 16t + 4kg + r
  const float kbias0 = sl_l2e * (float)(4 * kg - 1023) - 32.0f;

  // ===== Pass A: z[q=col] = sum_keys exp2(u - 32)  (swapped: mfma(K,Q)) ====
  float z0 = 0.f, z1 = 0.f, z2 = 0.f, z3 = 0.f;
  {
    short8 kc0 = *reinterpret_cast<const short8*>(Kb + col * 64 + 8 * kg);
    short8 kc1 = *reinterpret_cast<const short8*>(Kb + col * 64 + 8 * kg + 32);
#pragma unroll 4
    for (int kt = 0; kt < 64; ++kt) {
      const int tn = (kt + 1) & 63;  // prefetch next tile's K frags
      const unsigned short* kp = Kb + (16 * tn + col) * 64 + 8 * kg;
      short8 kn0 = *reinterpret_cast<const short8*>(kp);
      short8 kn1 = *reinterpret_cast<const short8*>(kp + 32);
      f32x4 acc = {0.f, 0.f, 0.f, 0.f};
      acc = __builtin_amdgcn_mfma_f32_16x16x32_bf16(kc0, qf0, acc, 0, 0, 0);
      acc = __builtin_amdgcn_mfma_f32_16x16x32_bf16(kc1, qf1, acc, 0, 0, 0);
      const float base = fmaf((float)(16 * kt), sl_l2e, kbias0);
      z0 += __builtin_amdgcn_exp2f(fmaf(acc[0], sc_l2e, base));
      z1 += __builtin_amdgcn_exp2f(fmaf(acc[1], sc_l2e, base + sl_l2e));
      z2 += __builtin_amdgcn_exp2f(fmaf(acc[2], sc_l2e, base + 2.f * sl_l2e));
      z3 += __builtin_amdgcn_exp2f(fmaf(acc[3], sc_l2e, base + 3.f * sl_l2e));
      kc0 = kn0;
      kc1 = kn1;
    }
  }
  float z = (z0 + z1) + (z2 + z3);
  z += __shfl_xor(z, 16, 64);
  z += __shfl_xor(z, 32, 64);
  const float minv = 1.0f / z;

  // ===== Pass B: QK -> P (regs) -> {global store, PV via 16x16x16} =====
  f32x4 oacc[4];
#pragma unroll
  for (int et = 0; et < 4; ++et) oacc[et] = (f32x4){0.f, 0.f, 0.f, 0.f};

  float* Pb = Pout + ((size_t)(b * H_ + h) * L_ + q0 + 16 * w) * L_ +
              (size_t)col * L_ + 4 * kg;

  {
    short8 kc0 = *reinterpret_cast<const short8*>(Kb + col * 64 + 8 * kg);
    short8 kc1 = *reinterpret_cast<const short8*>(Kb + col * 64 + 8 * kg + 32);
#pragma unroll 2
    for (int kt = 0; kt < 64; ++kt) {
      const int tn = (kt + 1) & 63;
      const unsigned short* kp = Kb + (16 * tn + col) * 64 + 8 * kg;
      short8 kn0 = *reinterpret_cast<const short8*>(kp);
      short8 kn1 = *reinterpret_cast<const short8*>(kp + 32);
      f32x4 acc = {0.f, 0.f, 0.f, 0.f};
      acc = __builtin_amdgcn_mfma_f32_16x16x32_bf16(kc0, qf0, acc, 0, 0, 0);
      acc = __builtin_amdgcn_mfma_f32_16x16x32_bf16(kc1, qf1, acc, 0, 0, 0);
      kc0 = kn0;
      kc1 = kn1;
      // V^T fragments for this 16-key tile (independent of acc)
      short4v vf[4];
#pragma unroll
      for (int et = 0; et < 4; ++et) {
        vf[et] = *reinterpret_cast<const short4v*>(
            &VTb[(size_t)(16 * et + col) * L_ + 16 * kt + 4 * kg]);
      }
      const float base = fmaf((float)(16 * kt), sl_l2e, kbias0);
      f32x4 pf;
      pf[0] = __builtin_amdgcn_exp2f(fmaf(acc[0], sc_l2e, base)) * minv;
      pf[1] = __builtin_amdgcn_exp2f(fmaf(acc[1], sc_l2e, base + sl_l2e)) * minv;
      pf[2] =
          __builtin_amdgcn_exp2f(fmaf(acc[2], sc_l2e, base + 2.f * sl_l2e)) * minv;
      pf[3] =
          __builtin_amdgcn_exp2f(fmaf(acc[3], sc_l2e, base + 3.f * sl_l2e)) * minv;
      // coalesced P store straight from D-frag (16 rows x 64B per instr)
      __builtin_nontemporal_store(pf, reinterpret_cast<f32x4*>(Pb + 16 * kt));
      // pack to bf16 A-frag (k = 4*kg + j == this lane's keys) and PV
      short4v pa = {(short)f2bf(pf[0]), (short)f2bf(pf[1]), (short)f2bf(pf[2]),
                    (short)f2bf(pf[3])};
#pragma unroll
      for (int et = 0; et < 4; ++et) oacc[et] = mfma16(pa, vf[et], oacc[et]);
    }
  }

  // ---- write O: q = q0+16w+4kg+r, e = 16et+col ----
  float* Vo = Vout + (((size_t)b * L_ + q0 + 16 * w) * H_ + h) * E_;
#pragma unroll
  for (int et = 0; et < 4; ++et) {
#pragma unroll
    for (int r = 0; r < 4; ++r) {
      __builtin_nontemporal_store(oacc[et][r],
                                  &Vo[(4 * kg + r) * RSTRIDE + 16 * et + col]);
    }
  }
}

extern "C" void kernel_launch(void* const* d_in, const int* in_sizes, int n_in,
                              void* d_out, int out_size, void* d_ws,
                              size_t ws_size, hipStream_t stream) {
  const float* Q = (const float*)d_in[0];
  const float* K = (const float*)d_in[1];
  const float* V = (const float*)d_in[2];
  float* out = (float*)d_out;
  float* Vo = out;                              // [B,L,H,E]
  float* Po = out + (size_t)B_ * L_ * H_ * E_;  // [B,H,L,L]
  unsigned short* Kbf = (unsigned short*)d_ws;  // 8 MB
  unsigned short* VTbf = Kbf + (size_t)B_ * H_ * L_ * E_;  // 8 MB
  hipLaunchKernelGGL(prep_kv, dim3(16 * B_ * H_), dim3(256), 0, stream, K, V,
                     Kbf, VTbf);
  hipLaunchKernelGGL(alibi_attn, dim3((L_ / QBLK) * H_ * B_), dim3(256), 0,
                     stream, Q, Kbf, VTbf, Vo, Po);
}